// Round 7
// baseline (308.362 us; speedup 1.0000x reference)
//
#include <hip/hip_runtime.h>
#include <climits>

#define VOXD 25
#define SLOT3 (VOXD*VOXD*VOXD)      // 15625
#define SLOTS (2*SLOT3)             // 31250
#define NCLS 8
#define NCODE 16
#define NBLK ((SLOTS + 255) / 256)  // 123
#define HB 2048                     // radix bins (11 bits)
#define BPC 64                      // fallback blocks per code (grid = 1024)
#define TILE 1024                   // cluster tile entries in LDS
#define CSTRIDE SLOT3               // per-code bucket capacity

struct Scalars {
  double hub;
  double cosSum;
  int n1;
  int nmd;
  float thresh;
  int done;
  int done2;   // k_loss_sel finalize counter
};

__device__ __forceinline__ int voxslot(int b, int vx, int vy, int vz) {
  return ((b * VOXD + vx) * VOXD + vy) * VOXD + vz;
}

// 256-thread (4-wave) inclusive block scan; ws[4] shared scratch.
__device__ __forceinline__ int block_scan256(int v, int* ws) {
  int lane = threadIdx.x & 63, w = threadIdx.x >> 6;
  int s = v;
  #pragma unroll
  for (int off = 1; off < 64; off <<= 1) {
    int t = __shfl_up(s, off, 64);
    if (lane >= off) s += t;
  }
  if (lane == 63) ws[w] = s;
  __syncthreads();
  int add = 0;
  #pragma unroll
  for (int q = 0; q < 4; ++q) if (q < w) add += ws[q];
  __syncthreads();
  return s + add;
}

// ---------------- K1: scatter with packed integer-exact atomics ------------------
__global__ void k_scatter(const float* __restrict__ grid, const int* __restrict__ label,
                          const int* __restrict__ batch,
                          unsigned long long* vA, unsigned long long* vB, int* lmask,
                          int* blCnt, float* blSum, int n) {
  __shared__ int sCnt[NCODE];
  __shared__ float sSum[3 * NCODE];
  int tid = threadIdx.x;
  if (tid < NCODE) sCnt[tid] = 0;
  if (tid < 3 * NCODE) sSum[tid] = 0.f;
  __syncthreads();
  int i = blockIdx.x * blockDim.x + tid;
  if (i < n) {
    float gx = grid[3*i], gy = grid[3*i+1], gz = grid[3*i+2];
    int ix = (int)gx, iy = (int)gy, iz = (int)gz;   // coords are exact small ints
    int vx = (int)floorf(gx * (1.0f/16.0f));
    int vy = (int)floorf(gy * (1.0f/16.0f));
    int vz = (int)floorf(gz * (1.0f/16.0f));
    int b = batch[i], l = label[i];
    int s = voxslot(b, vx, vy, vz);
    atomicAdd(&vA[s], ((unsigned long long)(unsigned)ix << 32) | (unsigned)iy);
    atomicAdd(&vB[s], ((unsigned long long)(unsigned)iz << 24) | 1ULL);
    atomicOr(&lmask[s], 1 << l);
    int bl = b * NCLS + l;
    atomicAdd(&sCnt[bl], 1);
    atomicAdd(&sSum[3*bl], gx); atomicAdd(&sSum[3*bl+1], gy); atomicAdd(&sSum[3*bl+2], gz);
  }
  __syncthreads();
  if (tid < NCODE && sCnt[tid] != 0) atomicAdd(&blCnt[tid], sCnt[tid]);
  if (tid < 3 * NCODE && sSum[tid] != 0.f) atomicAdd(&blSum[tid], sSum[tid]);
}

// ---------------- K2: decode tables -> slot float4 + per-code bucket append ------
// pC = {x, y, z, slot_bits}; c2 recomputed bit-exactly at fallback staging.
__global__ void k_prep(const unsigned long long* vA, const unsigned long long* vB,
                       const int* lmask, float4* ctr, float4* pC, int* codeCnt) {
  __shared__ int lc[NCODE];
  __shared__ int lb[NCODE];
  int tid = threadIdx.x;
  if (tid < NCODE) lc[tid] = 0;
  __syncthreads();
  int s = blockIdx.x * 256 + tid;
  int code = -1, lpos = 0;
  float4 v = make_float4(0.f, 0.f, 0.f, __int_as_float(-2));
  if (s < SLOTS) {
    unsigned long long bq = vB[s];
    unsigned c = (unsigned)(bq & 0xFFFFFFULL);
    if (c > 0) {
      unsigned long long aq = vA[s];
      float fc = (float)c;
      float cx = __fdiv_rn((float)(unsigned)(aq >> 32), fc);
      float cy = __fdiv_rn((float)(unsigned)(aq & 0xFFFFFFFFULL), fc);
      float cz = __fdiv_rn((float)(unsigned)(bq >> 24), fc);
      int m = lmask[s];
      bool pure = (m & (m - 1)) == 0;
      int lbl = __ffs(m) - 1;
      v = make_float4(cx, cy, cz, __int_as_float(pure ? lbl : -1));
      if (pure) {
        code = (s / SLOT3) * NCLS + lbl;
        lpos = atomicAdd(&lc[code], 1);
      }
    }
    ctr[s] = v;
  }
  __syncthreads();
  if (tid < NCODE) lb[tid] = (lc[tid] > 0) ? atomicAdd(&codeCnt[tid], lc[tid]) : 0;
  __syncthreads();
  if (code >= 0) {
    int pos = code * CSTRIDE + lb[code] + lpos;
    pC[pos] = make_float4(v.x, v.y, v.z, __int_as_float(s));
  }
}

// ---------------- K3: probe targets + per-code miss lists + LDS hist -------------
// Legacy (harness-verified).
__global__ void k_targets(const float* __restrict__ grid, const int* __restrict__ label,
                          const int* __restrict__ batch,
                          const float4* __restrict__ ctr,
                          const int* __restrict__ blCnt, const float* __restrict__ blSum,
                          float* tgt, float* mag, int* ghist,
                          int* missPart, int* missCnt, int mstride, int n) {
  __shared__ int wCnt[4][NCODE];
  __shared__ int gBase[NCODE];
  __shared__ int h[HB];
  int tid = threadIdx.x, lane = tid & 63, w = tid >> 6;
  for (int t = tid; t < HB; t += 256) h[t] = 0;
  __syncthreads();
  int i = blockIdx.x * blockDim.x + tid;
  bool active = (i < n);
  bool miss = false;
  int mcode = -1;

  if (active) {
    float gx = grid[3*i], gy = grid[3*i+1], gz = grid[3*i+2];
    int vx = (int)floorf(gx * (1.0f/16.0f));
    int vy = (int)floorf(gy * (1.0f/16.0f));
    int vz = (int)floorf(gz * (1.0f/16.0f));
    int b = batch[i], l = label[i];
    int s = voxslot(b, vx, vy, vz);

    float4 own = ctr[s];
    bool purept = (__float_as_int(own.w) >= 0);

    int bl = b * NCLS + l;
    float fbc = (float)max(blCnt[bl], 1);
    float gcx = __fdiv_rn(blSum[3*bl],   fbc);
    float gcy = __fdiv_rn(blSum[3*bl+1], fbc);
    float gcz = __fdiv_rn(blSum[3*bl+2], fbc);

    float dx = __fsub_rn(gcx, own.x);
    float dy = __fsub_rn(gcy, own.y);
    float dz = __fsub_rn(gcz, own.z);
    int sgx = (dx > 0.f) ? 1 : ((dx < 0.f) ? -1 : 0);
    int sgy = (dy > 0.f) ? 1 : ((dy < 0.f) ? -1 : 0);
    int sgz = (dz > 0.f) ? 1 : ((dz < 0.f) ? -1 : 0);

    int ax1 = vx + sgx,     ay1 = vy + sgy,     az1 = vz + sgz;
    int ax2 = vx + 2 * sgx, ay2 = vy + 2 * sgy, az2 = vz + 2 * sgz;
    bool v1 = (unsigned)ax1 < (unsigned)VOXD && (unsigned)ay1 < (unsigned)VOXD &&
              (unsigned)az1 < (unsigned)VOXD;
    bool v2 = (unsigned)ax2 < (unsigned)VOXD && (unsigned)ay2 < (unsigned)VOXD &&
              (unsigned)az2 < (unsigned)VOXD;

    float4 q1 = make_float4(0.f, 0.f, 0.f, __int_as_float(-3));
    float4 q2 = q1;
    if (v1) q1 = ctr[voxslot(b, ax1, ay1, az1)];
    if (v2) q2 = ctr[voxslot(b, ax2, ay2, az2)];

    bool hit1 = v1 && (__float_as_int(q1.w) == l);
    bool hit2 = v2 && (__float_as_int(q2.w) == l);
    bool hit = hit1 || hit2;

    float tx = hit1 ? q1.x : (hit2 ? q2.x : gx);
    float ty = hit1 ? q1.y : (hit2 ? q2.y : gy);
    float tz = hit1 ? q1.z : (hit2 ? q2.z : gz);

    tgt[3*i] = tx; tgt[3*i+1] = ty; tgt[3*i+2] = tz;
    miss = (!purept && !hit);
    if (miss) {
      mcode = bl;
    } else {
      float tox = __fsub_rn(tx, gx), toy = __fsub_rn(ty, gy), toz = __fsub_rn(tz, gz);
      float ssq = __fadd_rn(__fadd_rn(__fmul_rn(tox,tox), __fmul_rn(toy,toy)),
                            __fmul_rn(toz,toz));
      float m = (ssq > 0.f) ? sqrtf(ssq) : 0.f;
      mag[i] = m;
      atomicAdd(&h[__float_as_uint(m) >> 21], 1);
    }
  }
  int myrank = 0;
  #pragma unroll
  for (int c = 0; c < NCODE; ++c) {
    unsigned long long mb = __ballot(mcode == c);
    if (lane == 0) wCnt[w][c] = __popcll(mb);
    if (mcode == c) myrank = __popcll(mb & ((1ULL << lane) - 1ULL));
  }
  __syncthreads();
  if (tid < NCODE) {
    int tot = wCnt[0][tid] + wCnt[1][tid] + wCnt[2][tid] + wCnt[3][tid];
    gBase[tid] = (tot > 0) ? atomicAdd(&missCnt[tid], tot) : 0;
  }
  __syncthreads();
  if (miss) {
    int base = gBase[mcode];
    for (int q = 0; q < 4; ++q) if (q < w) base += wCnt[q][mcode];
    missPart[mcode * mstride + base + myrank] = i;
  }
  for (int t = tid; t < HB; t += 256) {
    int c = h[t];
    if (c != 0) atomicAdd(&ghist[t], c);
  }
}

// ---------------- K4: fallback, 64 misses/block, cluster-split across 4 waves ----
// Block = (code, miss-chunk of 64). All 4 waves hold the SAME 64 misses (one per
// lane); wave w scans the stride-4 interleave j = w, w+4, ... of the staged tile
// (broadcast LDS reads). Cross-wave exact combine via LDS min (keys unique by
// slot, min over disjoint subsets == global min => bit-identical result).
// Parallel work = misses x 4 waves => ~2.7 waves/SIMD (4x round 6).
__global__ void __launch_bounds__(256) k_fallback(
    const float* __restrict__ grid,
    const float4* __restrict__ pC,
    const float4* __restrict__ ctr,
    const int* __restrict__ codeCnt,
    const int* __restrict__ missPart, const int* __restrict__ missCnt,
    float* tgt, float* mag, int* ghist, int mstride) {
  __shared__ float4 tile4[TILE];                 // 16 KB {x,y,z,c2}
  __shared__ int    stile[TILE];                 //  4 KB slot ids
  __shared__ unsigned long long bkeyw[4][64];    //  2 KB per-wave best keys
  int tid = threadIdx.x, lane = tid & 63, w = tid >> 6;
  int c = blockIdx.x / BPC;
  int y = blockIdx.x % BPC;
  int mc = missCnt[c];
  if (y * 64 >= mc) return;                      // uniform early-out
  int cc = codeCnt[c];
  int j0 = c * CSTRIDE;
  const int* mlist = missPart + c * mstride;

  for (int t0 = y * 64; t0 < mc; t0 += BPC * 64) {
    int t = t0 + lane;
    bool valid = (t < mc);
    int idx = 0;
    float gx = 0.f, gy = 0.f, gz = 0.f, p2 = 0.f;
    if (valid) {
      idx = mlist[t];
      gx = grid[3*idx]; gy = grid[3*idx+1]; gz = grid[3*idx+2];
      p2 = __fadd_rn(__fadd_rn(__fmul_rn(gx,gx), __fmul_rn(gy,gy)),
                     __fmul_rn(gz,gz));
    }
    unsigned long long key = 0xFFFFFFFFFFFFFFFFULL;
    for (int tb = 0; tb < cc; tb += TILE) {
      int m = min(TILE, cc - tb);
      __syncthreads();
      for (int j = tid; j < m; j += 256) {
        float4 cl = pC[j0 + tb + j];
        float c2 = __fadd_rn(__fadd_rn(__fmul_rn(cl.x,cl.x), __fmul_rn(cl.y,cl.y)),
                             __fmul_rn(cl.z,cl.z));
        tile4[j] = make_float4(cl.x, cl.y, cl.z, c2);
        stile[j] = __float_as_int(cl.w);
      }
      __syncthreads();
      #pragma unroll 4
      for (int j = w; j < m; j += 4) {
        float4 cl = tile4[j];                    // broadcast read
        float dot = __fadd_rn(__fadd_rn(__fmul_rn(gx,cl.x), __fmul_rn(gy,cl.y)),
                              __fmul_rn(gz,cl.z));
        float d2 = __fadd_rn(__fsub_rn(p2, __fmul_rn(2.0f, dot)), cl.w);
        unsigned fb = __float_as_uint(d2);
        fb = (fb >> 31) ? ~fb : (fb | 0x80000000u);
        unsigned long long k2 = ((unsigned long long)fb << 32) | (unsigned)stile[j];
        if (k2 < key) key = k2;
      }
    }
    bkeyw[w][lane] = key;
    __syncthreads();
    if (w == 0 && valid) {
      unsigned long long k0 = bkeyw[0][lane];
      unsigned long long k1 = bkeyw[1][lane];
      unsigned long long k2_ = bkeyw[2][lane];
      unsigned long long k3 = bkeyw[3][lane];
      unsigned long long kk = k0 < k1 ? k0 : k1;
      unsigned long long kh = k2_ < k3 ? k2_ : k3;
      if (kh < kk) kk = kh;
      float mv = 0.f;
      if (cc > 0) {
        int slot = (int)(unsigned)(kk & 0xFFFFFFFFULL);
        float4 cl = ctr[slot];
        tgt[3*idx] = cl.x; tgt[3*idx+1] = cl.y; tgt[3*idx+2] = cl.z;
        float tox = __fsub_rn(cl.x, gx), toy = __fsub_rn(cl.y, gy),
              toz = __fsub_rn(cl.z, gz);
        float ssq = __fadd_rn(__fadd_rn(__fmul_rn(tox,tox), __fmul_rn(toy,toy)),
                              __fmul_rn(toz,toz));
        mv = (ssq > 0.f) ? sqrtf(ssq) : 0.f;
      }
      mag[idx] = mv;
      atomicAdd(&ghist[__float_as_uint(mv) >> 21], 1);
    }
    __syncthreads();                             // bkeyw reuse next pass
  }
}

// ---------------- K5: loss + exact quantile via boundary-bin deferral ------------
// (Round-6-verified.) Every block derives binA/binB from ghist; sure points are
// summed directly; only the ~1-3K boundary-bin points defer to the last block,
// which radix-selects va/vb over that small set and finishes.
__global__ void __launch_bounds__(256) k_loss_sel(
    const float* __restrict__ pred, const float* __restrict__ grid,
    const float* __restrict__ tgt, const float* __restrict__ mag,
    const int* __restrict__ ghist, uint2* defer, int* uCnt,
    Scalars* sc, float* out, int n, int nblocks, int r0, int r1, double tfrac) {
  __shared__ int h[HB];            // 8 KB (last block only)
  __shared__ int h2[HB];           // 8 KB
  __shared__ int ws[4];
  __shared__ int s_misc[8];
  __shared__ double shH[256];
  __shared__ double shC[256];
  __shared__ int shN[256];
  __shared__ int shM[256];
  __shared__ int sLast;
  __shared__ float sTh;
  int tid = threadIdx.x, lane = tid & 63;

  // ---- step 1: coarse bins from ghist (every block; identical results) ----
  int base8 = tid * 8;
  {
    int cbin[8];
    int s = 0;
    #pragma unroll
    for (int k = 0; k < 8; ++k) { cbin[k] = ghist[base8 + k]; s += cbin[k]; }
    int incl = block_scan256(s, ws);
    int lo = incl - s;
    if (r0 >= lo && r0 < lo + s) {
      int acc = lo;
      #pragma unroll
      for (int k = 0; k < 8; ++k) {
        if (r0 < acc + cbin[k]) { s_misc[0] = base8 + k; s_misc[1] = r0 - acc; break; }
        acc += cbin[k];
      }
    }
    if (r1 >= lo && r1 < lo + s) {
      int acc = lo;
      #pragma unroll
      for (int k = 0; k < 8; ++k) {
        if (r1 < acc + cbin[k]) { s_misc[2] = base8 + k; s_misc[3] = r1 - acc; break; }
        acc += cbin[k];
      }
    }
  }
  __syncthreads();
  int binA = s_misc[0], rA = s_misc[1], binB = s_misc[2], rB = s_misc[3];

  // ---- step 2: classify, sure sums (verified huber/cos arithmetic), defer ----
  int i = blockIdx.x * 256 + tid;
  double hub = 0.0, cs = 0.0;
  int c1 = 0, cmd = 0;
  bool dfr = false;
  unsigned bits = 0;
  if (i < n) {
    float m = mag[i];
    bits = __float_as_uint(m);
    int cb = (int)(bits >> 21);
    if (cb == binA || cb == binB) {
      dfr = true;
    } else if (cb < binA) {
      c1 = 1;
      float tox = __fsub_rn(tgt[3*i],   grid[3*i]);
      float toy = __fsub_rn(tgt[3*i+1], grid[3*i+1]);
      float toz = __fsub_rn(tgt[3*i+2], grid[3*i+2]);
      float px = pred[3*i], py = pred[3*i+1], pz = pred[3*i+2];
      float d0 = __fsub_rn(px, tox), d1 = __fsub_rn(py, toy), d2 = __fsub_rn(pz, toz);
      float a0 = fabsf(d0), a1 = fabsf(d1), a2 = fabsf(d2);
      float h0 = (a0 < 1.f) ? __fmul_rn(__fmul_rn(0.5f, d0), d0) : __fsub_rn(a0, 0.5f);
      float h1 = (a1 < 1.f) ? __fmul_rn(__fmul_rn(0.5f, d1), d1) : __fsub_rn(a1, 0.5f);
      float h2v = (a2 < 1.f) ? __fmul_rn(__fmul_rn(0.5f, d2), d2) : __fsub_rn(a2, 0.5f);
      hub = (double)h0 + (double)h1 + (double)h2v;
      if (m > 0.f) {
        cmd = 1;
        float ps = __fadd_rn(__fadd_rn(__fmul_rn(px,px), __fmul_rn(py,py)), __fmul_rn(pz,pz));
        float pn = (ps > 0.f) ? sqrtf(ps) : 0.f;
        float dotp = __fadd_rn(__fadd_rn(__fmul_rn(px,tox), __fmul_rn(py,toy)),
                               __fmul_rn(pz,toz));
        float den = fmaxf(__fmul_rn(pn, m), 1e-4f);
        cs = (double)__fdiv_rn(dotp, den);
      }
    }
  }
  {
    unsigned long long mb = __ballot(dfr);
    int mcp = __popcll(mb);
    int bs = 0;
    if (lane == 0 && mcp > 0) bs = atomicAdd(uCnt, mcp);
    bs = __shfl(bs, 0, 64);
    if (dfr) defer[bs + __popcll(mb & ((1ULL << lane) - 1ULL))] =
        make_uint2(bits, (unsigned)i);
  }
  shH[tid] = hub; shC[tid] = cs; shN[tid] = c1; shM[tid] = cmd;
  __syncthreads();
  for (int off = 128; off > 0; off >>= 1) {
    if (tid < off) {
      shH[tid] += shH[tid+off];
      shC[tid] += shC[tid+off];
      shN[tid] += shN[tid+off];
      shM[tid] += shM[tid+off];
    }
    __syncthreads();
  }
  if (tid == 0) {
    atomicAdd(&sc->hub, shH[0]);
    atomicAdd(&sc->cosSum, shC[0]);
    atomicAdd(&sc->n1, shN[0]);
    atomicAdd(&sc->nmd, shM[0]);
    __threadfence();
    int d = atomicAdd(&sc->done2, 1);
    sLast = (d == nblocks - 1) ? 1 : 0;
  }
  __syncthreads();
  if (!sLast) return;
  __threadfence();   // acquire: all blocks' defer writes + partial sums

  int U = atomicAdd(uCnt, 0);

  // ---- step 3: select va/vb among deferred values (verified radix arithmetic) ----
  for (int t = tid; t < HB; t += 256) { h[t] = 0; h2[t] = 0; }
  __syncthreads();
  for (int t = tid; t < U; t += 256) {
    unsigned v = defer[t].x;
    int cb = (int)(v >> 21);
    if (cb == binA) atomicAdd(&h[(v >> 10) & 0x7FF], 1);
    if (cb == binB) atomicAdd(&h2[(v >> 10) & 0x7FF], 1);
  }
  __syncthreads();
  {
    int a8[8], sA = 0;
    #pragma unroll
    for (int k = 0; k < 8; ++k) { a8[k] = h[base8 + k]; sA += a8[k]; }
    int inclA = block_scan256(sA, ws);
    int accA = inclA - sA;
    #pragma unroll
    for (int k = 0; k < 8; ++k) {
      if (rA >= accA && rA < accA + a8[k]) { s_misc[4] = base8 + k; s_misc[5] = rA - accA; }
      accA += a8[k];
    }
    int b8[8], sB = 0;
    #pragma unroll
    for (int k = 0; k < 8; ++k) { b8[k] = h2[base8 + k]; sB += b8[k]; }
    int inclB = block_scan256(sB, ws);
    int accB = inclB - sB;
    #pragma unroll
    for (int k = 0; k < 8; ++k) {
      if (rB >= accB && rB < accB + b8[k]) { s_misc[6] = base8 + k; s_misc[7] = rB - accB; }
      accB += b8[k];
    }
  }
  __syncthreads();
  int subA = s_misc[4], subRA = s_misc[5], subB = s_misc[6], subRB = s_misc[7];

  for (int t = tid; t < 1024; t += 256) { h[t] = 0; h2[t] = 0; }
  __syncthreads();
  for (int t = tid; t < U; t += 256) {
    unsigned v = defer[t].x;
    int cb = (int)(v >> 21);
    if (cb == binA && (int)((v >> 10) & 0x7FF) == subA) atomicAdd(&h[v & 0x3FF], 1);
    if (cb == binB && (int)((v >> 10) & 0x7FF) == subB) atomicAdd(&h2[v & 0x3FF], 1);
  }
  __syncthreads();
  {
    int base4 = tid * 4;
    int la[4], sA = 0;
    #pragma unroll
    for (int k = 0; k < 4; ++k) { la[k] = h[base4 + k]; sA += la[k]; }
    int inclA = block_scan256(sA, ws);
    int accA = inclA - sA;
    #pragma unroll
    for (int k = 0; k < 4; ++k) {
      if (subRA >= accA && subRA < accA + la[k]) s_misc[0] = base4 + k;
      accA += la[k];
    }
    int lb4[4], sB = 0;
    #pragma unroll
    for (int k = 0; k < 4; ++k) { lb4[k] = h2[base4 + k]; sB += lb4[k]; }
    int inclB = block_scan256(sB, ws);
    int accB = inclB - sB;
    #pragma unroll
    for (int k = 0; k < 4; ++k) {
      if (subRB >= accB && subRB < accB + lb4[k]) s_misc[1] = base4 + k;
      accB += lb4[k];
    }
  }
  __syncthreads();
  if (tid == 0) {
    unsigned va = ((unsigned)binA << 21) | ((unsigned)subA << 10) | (unsigned)s_misc[0];
    unsigned vb = ((unsigned)binB << 21) | ((unsigned)subB << 10) | (unsigned)s_misc[1];
    double a = (double)__uint_as_float(va);
    double b = (double)__uint_as_float(vb);
    double th = (tfrac >= 0.5) ? (b - (b - a) * (1.0 - tfrac)) : (a + (b - a) * tfrac);
    sc->thresh = (float)th;
    sTh = (float)th;
  }
  __syncthreads();
  float th = sTh;

  // ---- step 4: deferred-point loss (exact m <= th test, verified arithmetic) ----
  double hub2 = 0.0, cs2 = 0.0;
  int c12 = 0, cmd2 = 0;
  for (int t = tid; t < U; t += 256) {
    uint2 e = defer[t];
    float m = __uint_as_float(e.x);
    if (m <= th) {
      int idx = (int)e.y;
      c12 += 1;
      float tox = __fsub_rn(tgt[3*idx],   grid[3*idx]);
      float toy = __fsub_rn(tgt[3*idx+1], grid[3*idx+1]);
      float toz = __fsub_rn(tgt[3*idx+2], grid[3*idx+2]);
      float px = pred[3*idx], py = pred[3*idx+1], pz = pred[3*idx+2];
      float d0 = __fsub_rn(px, tox), d1 = __fsub_rn(py, toy), d2 = __fsub_rn(pz, toz);
      float a0 = fabsf(d0), a1 = fabsf(d1), a2 = fabsf(d2);
      float h0 = (a0 < 1.f) ? __fmul_rn(__fmul_rn(0.5f, d0), d0) : __fsub_rn(a0, 0.5f);
      float h1 = (a1 < 1.f) ? __fmul_rn(__fmul_rn(0.5f, d1), d1) : __fsub_rn(a1, 0.5f);
      float h2v = (a2 < 1.f) ? __fmul_rn(__fmul_rn(0.5f, d2), d2) : __fsub_rn(a2, 0.5f);
      hub2 += (double)h0 + (double)h1 + (double)h2v;
      if (m > 0.f) {
        cmd2 += 1;
        float ps = __fadd_rn(__fadd_rn(__fmul_rn(px,px), __fmul_rn(py,py)), __fmul_rn(pz,pz));
        float pn = (ps > 0.f) ? sqrtf(ps) : 0.f;
        float dotp = __fadd_rn(__fadd_rn(__fmul_rn(px,tox), __fmul_rn(py,toy)),
                               __fmul_rn(pz,toz));
        float den = fmaxf(__fmul_rn(pn, m), 1e-4f);
        cs2 += (double)__fdiv_rn(dotp, den);
      }
    }
  }
  shH[tid] = hub2; shC[tid] = cs2; shN[tid] = c12; shM[tid] = cmd2;
  __syncthreads();
  for (int off = 128; off > 0; off >>= 1) {
    if (tid < off) {
      shH[tid] += shH[tid+off];
      shC[tid] += shC[tid+off];
      shN[tid] += shN[tid+off];
      shM[tid] += shM[tid+off];
    }
    __syncthreads();
  }
  if (tid == 0) {
    double th_hub = atomicAdd(&sc->hub, 0.0) + shH[0];
    double th_cos = atomicAdd(&sc->cosSum, 0.0) + shC[0];
    int n1 = atomicAdd(&sc->n1, 0) + shN[0];
    int nmd = atomicAdd(&sc->nmd, 0) + shM[0];
    double l1 = (n1 > 0) ? th_hub / fmax((double)n1 * 3.0, 1.0) : 0.0;
    double ld = (nmd > 0) ? (1.0 - th_cos / fmax((double)nmd, 1.0)) : 0.0;
    out[0] = (float)l1;
    out[1] = (float)ld;
  }
}

extern "C" void kernel_launch(void* const* d_in, const int* in_sizes, int n_in,
                              void* d_out, int out_size, void* d_ws, size_t ws_size,
                              hipStream_t stream) {
  const float* pred  = (const float*)d_in[0];
  const float* grid  = (const float*)d_in[1];
  const int*   label = (const int*)d_in[2];
  const int*   batch = (const int*)d_in[3];
  int n = in_sizes[2];
  int mstride = n / 4;

  char* p = (char*)d_ws;
  auto take = [&](size_t bytes) -> char* {
    char* r = p;
    p += (bytes + 255) & ~(size_t)255;
    return r;
  };
  // ---- zero-init region (one hipMemsetAsync covers all of it) ----
  char* zbase = p;
  unsigned long long* vA = (unsigned long long*)take((size_t)SLOTS*8);
  unsigned long long* vB = (unsigned long long*)take((size_t)SLOTS*8);
  int*    lmask    = (int*)   take((size_t)SLOTS*4);
  int*    codeCnt  = (int*)   take(NCODE*4);
  int*    missCnt  = (int*)   take(NCODE*4);
  int*    blCnt    = (int*)   take(16*4);
  float*  blSum    = (float*) take(48*4);
  int*    ghist    = (int*)   take((size_t)HB*4);
  int*    uCnt     = (int*)   take(4);
  Scalars* sc      = (Scalars*)take(sizeof(Scalars));
  size_t zbytes = (size_t)(p - zbase);
  // ---- uninitialized buffers ----
  float4* ctr      = (float4*)take((size_t)SLOTS*16);
  float4* pC       = (float4*)take((size_t)NCODE*CSTRIDE*16);
  float*  tgt      = (float*) take((size_t)n*3*4);
  float*  mag      = (float*) take((size_t)n*4);
  int*    missPart = (int*)   take((size_t)NCODE*mstride*4);
  uint2*  defer    = (uint2*) take((size_t)n*8);

  int nb = (n + 255) / 256;
  int nfb = NCODE * BPC;

  double vi = 0.99 * (double)(n - 1);
  int r0 = (int)vi;
  int r1 = r0 + 1; if (r1 > n - 1) r1 = n - 1;
  double tfrac = vi - (double)r0;

  hipMemsetAsync(zbase, 0, zbytes, stream);
  k_scatter<<<nb, 256, 0, stream>>>(grid, label, batch, vA, vB, lmask,
                                    blCnt, blSum, n);
  k_prep<<<NBLK, 256, 0, stream>>>(vA, vB, lmask, ctr, pC, codeCnt);
  k_targets<<<nb, 256, 0, stream>>>(grid, label, batch, ctr, blCnt, blSum,
                                    tgt, mag, ghist, missPart, missCnt, mstride, n);
  k_fallback<<<nfb, 256, 0, stream>>>(grid, pC, ctr, codeCnt,
                                      missPart, missCnt, tgt, mag, ghist, mstride);
  k_loss_sel<<<nb, 256, 0, stream>>>(pred, grid, tgt, mag, ghist, defer, uCnt,
                                     sc, (float*)d_out, n, nb, r0, r1, tfrac);
}

// Round 8
// 142.282 us; speedup vs baseline: 2.1673x; 2.1673x over previous
//
#include <hip/hip_runtime.h>
#include <climits>

#define VOXD 25
#define SLOT3 (VOXD*VOXD*VOXD)      // 15625
#define SLOTS (2*SLOT3)             // 31250
#define NCLS 8
#define NCODE 16
#define NBLK ((SLOTS + 255) / 256)  // 123
#define HB 2048                     // radix bins (11 bits)
#define BPC 64                      // fallback blocks per code (grid = 1024)
#define TILE 1024                   // cluster tile entries in LDS
#define CSTRIDE SLOT3               // per-code bucket capacity

struct Scalars {
  double hub;
  double cosSum;
  int n1;
  int nmd;
  float thresh;
  int done;
  int done2;   // k_loss_sel finalize counter
};

__device__ __forceinline__ int voxslot(int b, int vx, int vy, int vz) {
  return ((b * VOXD + vx) * VOXD + vy) * VOXD + vz;
}

// 256-thread (4-wave) inclusive block scan; ws[4] shared scratch.
__device__ __forceinline__ int block_scan256(int v, int* ws) {
  int lane = threadIdx.x & 63, w = threadIdx.x >> 6;
  int s = v;
  #pragma unroll
  for (int off = 1; off < 64; off <<= 1) {
    int t = __shfl_up(s, off, 64);
    if (lane >= off) s += t;
  }
  if (lane == 63) ws[w] = s;
  __syncthreads();
  int add = 0;
  #pragma unroll
  for (int q = 0; q < 4; ++q) if (q < w) add += ws[q];
  __syncthreads();
  return s + add;
}

// ---------------- K1: scatter with packed integer-exact atomics ------------------
__global__ void k_scatter(const float* __restrict__ grid, const int* __restrict__ label,
                          const int* __restrict__ batch,
                          unsigned long long* vA, unsigned long long* vB, int* lmask,
                          int* blCnt, float* blSum, int n) {
  __shared__ int sCnt[NCODE];
  __shared__ float sSum[3 * NCODE];
  int tid = threadIdx.x;
  if (tid < NCODE) sCnt[tid] = 0;
  if (tid < 3 * NCODE) sSum[tid] = 0.f;
  __syncthreads();
  int i = blockIdx.x * blockDim.x + tid;
  if (i < n) {
    float gx = grid[3*i], gy = grid[3*i+1], gz = grid[3*i+2];
    int ix = (int)gx, iy = (int)gy, iz = (int)gz;   // coords are exact small ints
    int vx = (int)floorf(gx * (1.0f/16.0f));
    int vy = (int)floorf(gy * (1.0f/16.0f));
    int vz = (int)floorf(gz * (1.0f/16.0f));
    int b = batch[i], l = label[i];
    int s = voxslot(b, vx, vy, vz);
    atomicAdd(&vA[s], ((unsigned long long)(unsigned)ix << 32) | (unsigned)iy);
    atomicAdd(&vB[s], ((unsigned long long)(unsigned)iz << 24) | 1ULL);
    atomicOr(&lmask[s], 1 << l);
    int bl = b * NCLS + l;
    atomicAdd(&sCnt[bl], 1);
    atomicAdd(&sSum[3*bl], gx); atomicAdd(&sSum[3*bl+1], gy); atomicAdd(&sSum[3*bl+2], gz);
  }
  __syncthreads();
  if (tid < NCODE && sCnt[tid] != 0) atomicAdd(&blCnt[tid], sCnt[tid]);
  if (tid < 3 * NCODE && sSum[tid] != 0.f) atomicAdd(&blSum[tid], sSum[tid]);
}

// ---------------- K2: decode tables -> slot float4 + per-code bucket append ------
// pC = {x, y, z, slot_bits}; c2 recomputed bit-exactly at fallback staging.
__global__ void k_prep(const unsigned long long* vA, const unsigned long long* vB,
                       const int* lmask, float4* ctr, float4* pC, int* codeCnt) {
  __shared__ int lc[NCODE];
  __shared__ int lb[NCODE];
  int tid = threadIdx.x;
  if (tid < NCODE) lc[tid] = 0;
  __syncthreads();
  int s = blockIdx.x * 256 + tid;
  int code = -1, lpos = 0;
  float4 v = make_float4(0.f, 0.f, 0.f, __int_as_float(-2));
  if (s < SLOTS) {
    unsigned long long bq = vB[s];
    unsigned c = (unsigned)(bq & 0xFFFFFFULL);
    if (c > 0) {
      unsigned long long aq = vA[s];
      float fc = (float)c;
      float cx = __fdiv_rn((float)(unsigned)(aq >> 32), fc);
      float cy = __fdiv_rn((float)(unsigned)(aq & 0xFFFFFFFFULL), fc);
      float cz = __fdiv_rn((float)(unsigned)(bq >> 24), fc);
      int m = lmask[s];
      bool pure = (m & (m - 1)) == 0;
      int lbl = __ffs(m) - 1;
      v = make_float4(cx, cy, cz, __int_as_float(pure ? lbl : -1));
      if (pure) {
        code = (s / SLOT3) * NCLS + lbl;
        lpos = atomicAdd(&lc[code], 1);
      }
    }
    ctr[s] = v;
  }
  __syncthreads();
  if (tid < NCODE) lb[tid] = (lc[tid] > 0) ? atomicAdd(&codeCnt[tid], lc[tid]) : 0;
  __syncthreads();
  if (code >= 0) {
    int pos = code * CSTRIDE + lb[code] + lpos;
    pC[pos] = make_float4(v.x, v.y, v.z, __int_as_float(s));
  }
}

// ---------------- K3: probe targets + per-code miss lists + LDS hist -------------
// Legacy (harness-verified).
__global__ void k_targets(const float* __restrict__ grid, const int* __restrict__ label,
                          const int* __restrict__ batch,
                          const float4* __restrict__ ctr,
                          const int* __restrict__ blCnt, const float* __restrict__ blSum,
                          float* tgt, float* mag, int* ghist,
                          int* missPart, int* missCnt, int mstride, int n) {
  __shared__ int wCnt[4][NCODE];
  __shared__ int gBase[NCODE];
  __shared__ int h[HB];
  int tid = threadIdx.x, lane = tid & 63, w = tid >> 6;
  for (int t = tid; t < HB; t += 256) h[t] = 0;
  __syncthreads();
  int i = blockIdx.x * blockDim.x + tid;
  bool active = (i < n);
  bool miss = false;
  int mcode = -1;

  if (active) {
    float gx = grid[3*i], gy = grid[3*i+1], gz = grid[3*i+2];
    int vx = (int)floorf(gx * (1.0f/16.0f));
    int vy = (int)floorf(gy * (1.0f/16.0f));
    int vz = (int)floorf(gz * (1.0f/16.0f));
    int b = batch[i], l = label[i];
    int s = voxslot(b, vx, vy, vz);

    float4 own = ctr[s];
    bool purept = (__float_as_int(own.w) >= 0);

    int bl = b * NCLS + l;
    float fbc = (float)max(blCnt[bl], 1);
    float gcx = __fdiv_rn(blSum[3*bl],   fbc);
    float gcy = __fdiv_rn(blSum[3*bl+1], fbc);
    float gcz = __fdiv_rn(blSum[3*bl+2], fbc);

    float dx = __fsub_rn(gcx, own.x);
    float dy = __fsub_rn(gcy, own.y);
    float dz = __fsub_rn(gcz, own.z);
    int sgx = (dx > 0.f) ? 1 : ((dx < 0.f) ? -1 : 0);
    int sgy = (dy > 0.f) ? 1 : ((dy < 0.f) ? -1 : 0);
    int sgz = (dz > 0.f) ? 1 : ((dz < 0.f) ? -1 : 0);

    int ax1 = vx + sgx,     ay1 = vy + sgy,     az1 = vz + sgz;
    int ax2 = vx + 2 * sgx, ay2 = vy + 2 * sgy, az2 = vz + 2 * sgz;
    bool v1 = (unsigned)ax1 < (unsigned)VOXD && (unsigned)ay1 < (unsigned)VOXD &&
              (unsigned)az1 < (unsigned)VOXD;
    bool v2 = (unsigned)ax2 < (unsigned)VOXD && (unsigned)ay2 < (unsigned)VOXD &&
              (unsigned)az2 < (unsigned)VOXD;

    float4 q1 = make_float4(0.f, 0.f, 0.f, __int_as_float(-3));
    float4 q2 = q1;
    if (v1) q1 = ctr[voxslot(b, ax1, ay1, az1)];
    if (v2) q2 = ctr[voxslot(b, ax2, ay2, az2)];

    bool hit1 = v1 && (__float_as_int(q1.w) == l);
    bool hit2 = v2 && (__float_as_int(q2.w) == l);
    bool hit = hit1 || hit2;

    float tx = hit1 ? q1.x : (hit2 ? q2.x : gx);
    float ty = hit1 ? q1.y : (hit2 ? q2.y : gy);
    float tz = hit1 ? q1.z : (hit2 ? q2.z : gz);

    tgt[3*i] = tx; tgt[3*i+1] = ty; tgt[3*i+2] = tz;
    miss = (!purept && !hit);
    if (miss) {
      mcode = bl;
    } else {
      float tox = __fsub_rn(tx, gx), toy = __fsub_rn(ty, gy), toz = __fsub_rn(tz, gz);
      float ssq = __fadd_rn(__fadd_rn(__fmul_rn(tox,tox), __fmul_rn(toy,toy)),
                            __fmul_rn(toz,toz));
      float m = (ssq > 0.f) ? sqrtf(ssq) : 0.f;
      mag[i] = m;
      atomicAdd(&h[__float_as_uint(m) >> 21], 1);
    }
  }
  int myrank = 0;
  #pragma unroll
  for (int c = 0; c < NCODE; ++c) {
    unsigned long long mb = __ballot(mcode == c);
    if (lane == 0) wCnt[w][c] = __popcll(mb);
    if (mcode == c) myrank = __popcll(mb & ((1ULL << lane) - 1ULL));
  }
  __syncthreads();
  if (tid < NCODE) {
    int tot = wCnt[0][tid] + wCnt[1][tid] + wCnt[2][tid] + wCnt[3][tid];
    gBase[tid] = (tot > 0) ? atomicAdd(&missCnt[tid], tot) : 0;
  }
  __syncthreads();
  if (miss) {
    int base = gBase[mcode];
    for (int q = 0; q < 4; ++q) if (q < w) base += wCnt[q][mcode];
    missPart[mcode * mstride + base + myrank] = i;
  }
  for (int t = tid; t < HB; t += 256) {
    int c = h[t];
    if (c != 0) atomicAdd(&ghist[t], c);
  }
}

// ---------------- K4: fallback, 64 misses/block, cluster-split across 4 waves ----
// Round-7 structure (verified bit-exact) + ROUND-6's per-block LDS histogram
// restored (round 7's direct global ghist atomics serialized device-wide on a
// few hot bins -- 41.7 -> 187.7 us; Guideline 12).
__global__ void __launch_bounds__(256) k_fallback(
    const float* __restrict__ grid,
    const float4* __restrict__ pC,
    const float4* __restrict__ ctr,
    const int* __restrict__ codeCnt,
    const int* __restrict__ missPart, const int* __restrict__ missCnt,
    float* tgt, float* mag, int* ghist, int mstride) {
  __shared__ float4 tile4[TILE];                 // 16 KB {x,y,z,c2}
  __shared__ int    stile[TILE];                 //  4 KB slot ids
  __shared__ unsigned long long bkeyw[4][64];    //  2 KB per-wave best keys
  __shared__ int h[HB];                          //  8 KB per-block histogram
  int tid = threadIdx.x, lane = tid & 63, w = tid >> 6;
  int c = blockIdx.x / BPC;
  int y = blockIdx.x % BPC;
  int mc = missCnt[c];
  if (y * 64 >= mc) return;                      // uniform early-out (no hist yet)
  int cc = codeCnt[c];
  int j0 = c * CSTRIDE;
  const int* mlist = missPart + c * mstride;

  for (int t = tid; t < HB; t += 256) h[t] = 0;
  __syncthreads();

  for (int t0 = y * 64; t0 < mc; t0 += BPC * 64) {
    int t = t0 + lane;
    bool valid = (t < mc);
    int idx = 0;
    float gx = 0.f, gy = 0.f, gz = 0.f, p2 = 0.f;
    if (valid) {
      idx = mlist[t];
      gx = grid[3*idx]; gy = grid[3*idx+1]; gz = grid[3*idx+2];
      p2 = __fadd_rn(__fadd_rn(__fmul_rn(gx,gx), __fmul_rn(gy,gy)),
                     __fmul_rn(gz,gz));
    }
    unsigned long long key = 0xFFFFFFFFFFFFFFFFULL;
    for (int tb = 0; tb < cc; tb += TILE) {
      int m = min(TILE, cc - tb);
      __syncthreads();
      for (int j = tid; j < m; j += 256) {
        float4 cl = pC[j0 + tb + j];
        float c2 = __fadd_rn(__fadd_rn(__fmul_rn(cl.x,cl.x), __fmul_rn(cl.y,cl.y)),
                             __fmul_rn(cl.z,cl.z));
        tile4[j] = make_float4(cl.x, cl.y, cl.z, c2);
        stile[j] = __float_as_int(cl.w);
      }
      __syncthreads();
      #pragma unroll 4
      for (int j = w; j < m; j += 4) {
        float4 cl = tile4[j];                    // broadcast read
        float dot = __fadd_rn(__fadd_rn(__fmul_rn(gx,cl.x), __fmul_rn(gy,cl.y)),
                              __fmul_rn(gz,cl.z));
        float d2 = __fadd_rn(__fsub_rn(p2, __fmul_rn(2.0f, dot)), cl.w);
        unsigned fb = __float_as_uint(d2);
        fb = (fb >> 31) ? ~fb : (fb | 0x80000000u);
        unsigned long long k2 = ((unsigned long long)fb << 32) | (unsigned)stile[j];
        if (k2 < key) key = k2;
      }
    }
    bkeyw[w][lane] = key;
    __syncthreads();
    if (w == 0 && valid) {
      unsigned long long k0 = bkeyw[0][lane];
      unsigned long long k1 = bkeyw[1][lane];
      unsigned long long k2_ = bkeyw[2][lane];
      unsigned long long k3 = bkeyw[3][lane];
      unsigned long long kk = k0 < k1 ? k0 : k1;
      unsigned long long kh = k2_ < k3 ? k2_ : k3;
      if (kh < kk) kk = kh;
      float mv = 0.f;
      if (cc > 0) {
        int slot = (int)(unsigned)(kk & 0xFFFFFFFFULL);
        float4 cl = ctr[slot];
        tgt[3*idx] = cl.x; tgt[3*idx+1] = cl.y; tgt[3*idx+2] = cl.z;
        float tox = __fsub_rn(cl.x, gx), toy = __fsub_rn(cl.y, gy),
              toz = __fsub_rn(cl.z, gz);
        float ssq = __fadd_rn(__fadd_rn(__fmul_rn(tox,tox), __fmul_rn(toy,toy)),
                              __fmul_rn(toz,toz));
        mv = (ssq > 0.f) ? sqrtf(ssq) : 0.f;
      }
      mag[idx] = mv;
      atomicAdd(&h[__float_as_uint(mv) >> 21], 1);
    }
    __syncthreads();                             // bkeyw/h reuse next pass
  }

  // flush aggregated histogram (few hundred adds per block, spread over bins)
  for (int t = tid; t < HB; t += 256) {
    int cv = h[t];
    if (cv != 0) atomicAdd(&ghist[t], cv);
  }
}

// ---------------- K5: loss + exact quantile via boundary-bin deferral ------------
// (Round-6-verified.)
__global__ void __launch_bounds__(256) k_loss_sel(
    const float* __restrict__ pred, const float* __restrict__ grid,
    const float* __restrict__ tgt, const float* __restrict__ mag,
    const int* __restrict__ ghist, uint2* defer, int* uCnt,
    Scalars* sc, float* out, int n, int nblocks, int r0, int r1, double tfrac) {
  __shared__ int h[HB];            // 8 KB (last block only)
  __shared__ int h2[HB];           // 8 KB
  __shared__ int ws[4];
  __shared__ int s_misc[8];
  __shared__ double shH[256];
  __shared__ double shC[256];
  __shared__ int shN[256];
  __shared__ int shM[256];
  __shared__ int sLast;
  __shared__ float sTh;
  int tid = threadIdx.x, lane = tid & 63;

  // ---- step 1: coarse bins from ghist (every block; identical results) ----
  int base8 = tid * 8;
  {
    int cbin[8];
    int s = 0;
    #pragma unroll
    for (int k = 0; k < 8; ++k) { cbin[k] = ghist[base8 + k]; s += cbin[k]; }
    int incl = block_scan256(s, ws);
    int lo = incl - s;
    if (r0 >= lo && r0 < lo + s) {
      int acc = lo;
      #pragma unroll
      for (int k = 0; k < 8; ++k) {
        if (r0 < acc + cbin[k]) { s_misc[0] = base8 + k; s_misc[1] = r0 - acc; break; }
        acc += cbin[k];
      }
    }
    if (r1 >= lo && r1 < lo + s) {
      int acc = lo;
      #pragma unroll
      for (int k = 0; k < 8; ++k) {
        if (r1 < acc + cbin[k]) { s_misc[2] = base8 + k; s_misc[3] = r1 - acc; break; }
        acc += cbin[k];
      }
    }
  }
  __syncthreads();
  int binA = s_misc[0], rA = s_misc[1], binB = s_misc[2], rB = s_misc[3];

  // ---- step 2: classify, sure sums (verified huber/cos arithmetic), defer ----
  int i = blockIdx.x * 256 + tid;
  double hub = 0.0, cs = 0.0;
  int c1 = 0, cmd = 0;
  bool dfr = false;
  unsigned bits = 0;
  if (i < n) {
    float m = mag[i];
    bits = __float_as_uint(m);
    int cb = (int)(bits >> 21);
    if (cb == binA || cb == binB) {
      dfr = true;
    } else if (cb < binA) {
      c1 = 1;
      float tox = __fsub_rn(tgt[3*i],   grid[3*i]);
      float toy = __fsub_rn(tgt[3*i+1], grid[3*i+1]);
      float toz = __fsub_rn(tgt[3*i+2], grid[3*i+2]);
      float px = pred[3*i], py = pred[3*i+1], pz = pred[3*i+2];
      float d0 = __fsub_rn(px, tox), d1 = __fsub_rn(py, toy), d2 = __fsub_rn(pz, toz);
      float a0 = fabsf(d0), a1 = fabsf(d1), a2 = fabsf(d2);
      float h0 = (a0 < 1.f) ? __fmul_rn(__fmul_rn(0.5f, d0), d0) : __fsub_rn(a0, 0.5f);
      float h1 = (a1 < 1.f) ? __fmul_rn(__fmul_rn(0.5f, d1), d1) : __fsub_rn(a1, 0.5f);
      float h2v = (a2 < 1.f) ? __fmul_rn(__fmul_rn(0.5f, d2), d2) : __fsub_rn(a2, 0.5f);
      hub = (double)h0 + (double)h1 + (double)h2v;
      if (m > 0.f) {
        cmd = 1;
        float ps = __fadd_rn(__fadd_rn(__fmul_rn(px,px), __fmul_rn(py,py)), __fmul_rn(pz,pz));
        float pn = (ps > 0.f) ? sqrtf(ps) : 0.f;
        float dotp = __fadd_rn(__fadd_rn(__fmul_rn(px,tox), __fmul_rn(py,toy)),
                               __fmul_rn(pz,toz));
        float den = fmaxf(__fmul_rn(pn, m), 1e-4f);
        cs = (double)__fdiv_rn(dotp, den);
      }
    }
  }
  {
    unsigned long long mb = __ballot(dfr);
    int mcp = __popcll(mb);
    int bs = 0;
    if (lane == 0 && mcp > 0) bs = atomicAdd(uCnt, mcp);
    bs = __shfl(bs, 0, 64);
    if (dfr) defer[bs + __popcll(mb & ((1ULL << lane) - 1ULL))] =
        make_uint2(bits, (unsigned)i);
  }
  shH[tid] = hub; shC[tid] = cs; shN[tid] = c1; shM[tid] = cmd;
  __syncthreads();
  for (int off = 128; off > 0; off >>= 1) {
    if (tid < off) {
      shH[tid] += shH[tid+off];
      shC[tid] += shC[tid+off];
      shN[tid] += shN[tid+off];
      shM[tid] += shM[tid+off];
    }
    __syncthreads();
  }
  if (tid == 0) {
    atomicAdd(&sc->hub, shH[0]);
    atomicAdd(&sc->cosSum, shC[0]);
    atomicAdd(&sc->n1, shN[0]);
    atomicAdd(&sc->nmd, shM[0]);
    __threadfence();
    int d = atomicAdd(&sc->done2, 1);
    sLast = (d == nblocks - 1) ? 1 : 0;
  }
  __syncthreads();
  if (!sLast) return;
  __threadfence();   // acquire: all blocks' defer writes + partial sums

  int U = atomicAdd(uCnt, 0);

  // ---- step 3: select va/vb among deferred values (verified radix arithmetic) ----
  for (int t = tid; t < HB; t += 256) { h[t] = 0; h2[t] = 0; }
  __syncthreads();
  for (int t = tid; t < U; t += 256) {
    unsigned v = defer[t].x;
    int cb = (int)(v >> 21);
    if (cb == binA) atomicAdd(&h[(v >> 10) & 0x7FF], 1);
    if (cb == binB) atomicAdd(&h2[(v >> 10) & 0x7FF], 1);
  }
  __syncthreads();
  {
    int a8[8], sA = 0;
    #pragma unroll
    for (int k = 0; k < 8; ++k) { a8[k] = h[base8 + k]; sA += a8[k]; }
    int inclA = block_scan256(sA, ws);
    int accA = inclA - sA;
    #pragma unroll
    for (int k = 0; k < 8; ++k) {
      if (rA >= accA && rA < accA + a8[k]) { s_misc[4] = base8 + k; s_misc[5] = rA - accA; }
      accA += a8[k];
    }
    int b8[8], sB = 0;
    #pragma unroll
    for (int k = 0; k < 8; ++k) { b8[k] = h2[base8 + k]; sB += b8[k]; }
    int inclB = block_scan256(sB, ws);
    int accB = inclB - sB;
    #pragma unroll
    for (int k = 0; k < 8; ++k) {
      if (rB >= accB && rB < accB + b8[k]) { s_misc[6] = base8 + k; s_misc[7] = rB - accB; }
      accB += b8[k];
    }
  }
  __syncthreads();
  int subA = s_misc[4], subRA = s_misc[5], subB = s_misc[6], subRB = s_misc[7];

  for (int t = tid; t < 1024; t += 256) { h[t] = 0; h2[t] = 0; }
  __syncthreads();
  for (int t = tid; t < U; t += 256) {
    unsigned v = defer[t].x;
    int cb = (int)(v >> 21);
    if (cb == binA && (int)((v >> 10) & 0x7FF) == subA) atomicAdd(&h[v & 0x3FF], 1);
    if (cb == binB && (int)((v >> 10) & 0x7FF) == subB) atomicAdd(&h2[v & 0x3FF], 1);
  }
  __syncthreads();
  {
    int base4 = tid * 4;
    int la[4], sA = 0;
    #pragma unroll
    for (int k = 0; k < 4; ++k) { la[k] = h[base4 + k]; sA += la[k]; }
    int inclA = block_scan256(sA, ws);
    int accA = inclA - sA;
    #pragma unroll
    for (int k = 0; k < 4; ++k) {
      if (subRA >= accA && subRA < accA + la[k]) s_misc[0] = base4 + k;
      accA += la[k];
    }
    int lb4[4], sB = 0;
    #pragma unroll
    for (int k = 0; k < 4; ++k) { lb4[k] = h2[base4 + k]; sB += lb4[k]; }
    int inclB = block_scan256(sB, ws);
    int accB = inclB - sB;
    #pragma unroll
    for (int k = 0; k < 4; ++k) {
      if (subRB >= accB && subRB < accB + lb4[k]) s_misc[1] = base4 + k;
      accB += lb4[k];
    }
  }
  __syncthreads();
  if (tid == 0) {
    unsigned va = ((unsigned)binA << 21) | ((unsigned)subA << 10) | (unsigned)s_misc[0];
    unsigned vb = ((unsigned)binB << 21) | ((unsigned)subB << 10) | (unsigned)s_misc[1];
    double a = (double)__uint_as_float(va);
    double b = (double)__uint_as_float(vb);
    double th = (tfrac >= 0.5) ? (b - (b - a) * (1.0 - tfrac)) : (a + (b - a) * tfrac);
    sc->thresh = (float)th;
    sTh = (float)th;
  }
  __syncthreads();
  float th = sTh;

  // ---- step 4: deferred-point loss (exact m <= th test, verified arithmetic) ----
  double hub2 = 0.0, cs2 = 0.0;
  int c12 = 0, cmd2 = 0;
  for (int t = tid; t < U; t += 256) {
    uint2 e = defer[t];
    float m = __uint_as_float(e.x);
    if (m <= th) {
      int idx = (int)e.y;
      c12 += 1;
      float tox = __fsub_rn(tgt[3*idx],   grid[3*idx]);
      float toy = __fsub_rn(tgt[3*idx+1], grid[3*idx+1]);
      float toz = __fsub_rn(tgt[3*idx+2], grid[3*idx+2]);
      float px = pred[3*idx], py = pred[3*idx+1], pz = pred[3*idx+2];
      float d0 = __fsub_rn(px, tox), d1 = __fsub_rn(py, toy), d2 = __fsub_rn(pz, toz);
      float a0 = fabsf(d0), a1 = fabsf(d1), a2 = fabsf(d2);
      float h0 = (a0 < 1.f) ? __fmul_rn(__fmul_rn(0.5f, d0), d0) : __fsub_rn(a0, 0.5f);
      float h1 = (a1 < 1.f) ? __fmul_rn(__fmul_rn(0.5f, d1), d1) : __fsub_rn(a1, 0.5f);
      float h2v = (a2 < 1.f) ? __fmul_rn(__fmul_rn(0.5f, d2), d2) : __fsub_rn(a2, 0.5f);
      hub2 += (double)h0 + (double)h1 + (double)h2v;
      if (m > 0.f) {
        cmd2 += 1;
        float ps = __fadd_rn(__fadd_rn(__fmul_rn(px,px), __fmul_rn(py,py)), __fmul_rn(pz,pz));
        float pn = (ps > 0.f) ? sqrtf(ps) : 0.f;
        float dotp = __fadd_rn(__fadd_rn(__fmul_rn(px,tox), __fmul_rn(py,toy)),
                               __fmul_rn(pz,toz));
        float den = fmaxf(__fmul_rn(pn, m), 1e-4f);
        cs2 += (double)__fdiv_rn(dotp, den);
      }
    }
  }
  shH[tid] = hub2; shC[tid] = cs2; shN[tid] = c12; shM[tid] = cmd2;
  __syncthreads();
  for (int off = 128; off > 0; off >>= 1) {
    if (tid < off) {
      shH[tid] += shH[tid+off];
      shC[tid] += shC[tid+off];
      shN[tid] += shN[tid+off];
      shM[tid] += shM[tid+off];
    }
    __syncthreads();
  }
  if (tid == 0) {
    double th_hub = atomicAdd(&sc->hub, 0.0) + shH[0];
    double th_cos = atomicAdd(&sc->cosSum, 0.0) + shC[0];
    int n1 = atomicAdd(&sc->n1, 0) + shN[0];
    int nmd = atomicAdd(&sc->nmd, 0) + shM[0];
    double l1 = (n1 > 0) ? th_hub / fmax((double)n1 * 3.0, 1.0) : 0.0;
    double ld = (nmd > 0) ? (1.0 - th_cos / fmax((double)nmd, 1.0)) : 0.0;
    out[0] = (float)l1;
    out[1] = (float)ld;
  }
}

extern "C" void kernel_launch(void* const* d_in, const int* in_sizes, int n_in,
                              void* d_out, int out_size, void* d_ws, size_t ws_size,
                              hipStream_t stream) {
  const float* pred  = (const float*)d_in[0];
  const float* grid  = (const float*)d_in[1];
  const int*   label = (const int*)d_in[2];
  const int*   batch = (const int*)d_in[3];
  int n = in_sizes[2];
  int mstride = n / 4;

  char* p = (char*)d_ws;
  auto take = [&](size_t bytes) -> char* {
    char* r = p;
    p += (bytes + 255) & ~(size_t)255;
    return r;
  };
  // ---- zero-init region (one hipMemsetAsync covers all of it) ----
  char* zbase = p;
  unsigned long long* vA = (unsigned long long*)take((size_t)SLOTS*8);
  unsigned long long* vB = (unsigned long long*)take((size_t)SLOTS*8);
  int*    lmask    = (int*)   take((size_t)SLOTS*4);
  int*    codeCnt  = (int*)   take(NCODE*4);
  int*    missCnt  = (int*)   take(NCODE*4);
  int*    blCnt    = (int*)   take(16*4);
  float*  blSum    = (float*) take(48*4);
  int*    ghist    = (int*)   take((size_t)HB*4);
  int*    uCnt     = (int*)   take(4);
  Scalars* sc      = (Scalars*)take(sizeof(Scalars));
  size_t zbytes = (size_t)(p - zbase);
  // ---- uninitialized buffers ----
  float4* ctr      = (float4*)take((size_t)SLOTS*16);
  float4* pC       = (float4*)take((size_t)NCODE*CSTRIDE*16);
  float*  tgt      = (float*) take((size_t)n*3*4);
  float*  mag      = (float*) take((size_t)n*4);
  int*    missPart = (int*)   take((size_t)NCODE*mstride*4);
  uint2*  defer    = (uint2*) take((size_t)n*8);

  int nb = (n + 255) / 256;
  int nfb = NCODE * BPC;

  double vi = 0.99 * (double)(n - 1);
  int r0 = (int)vi;
  int r1 = r0 + 1; if (r1 > n - 1) r1 = n - 1;
  double tfrac = vi - (double)r0;

  hipMemsetAsync(zbase, 0, zbytes, stream);
  k_scatter<<<nb, 256, 0, stream>>>(grid, label, batch, vA, vB, lmask,
                                    blCnt, blSum, n);
  k_prep<<<NBLK, 256, 0, stream>>>(vA, vB, lmask, ctr, pC, codeCnt);
  k_targets<<<nb, 256, 0, stream>>>(grid, label, batch, ctr, blCnt, blSum,
                                    tgt, mag, ghist, missPart, missCnt, mstride, n);
  k_fallback<<<nfb, 256, 0, stream>>>(grid, pC, ctr, codeCnt,
                                      missPart, missCnt, tgt, mag, ghist, mstride);
  k_loss_sel<<<nb, 256, 0, stream>>>(pred, grid, tgt, mag, ghist, defer, uCnt,
                                     sc, (float*)d_out, n, nb, r0, r1, tfrac);
}

// Round 9
// 138.320 us; speedup vs baseline: 2.2293x; 1.0286x over previous
//
#include <hip/hip_runtime.h>
#include <climits>

#define VOXD 25
#define SLOT3 (VOXD*VOXD*VOXD)      // 15625
#define SLOTS (2*SLOT3)             // 31250
#define NCLS 8
#define NCODE 16
#define NBLK ((SLOTS + 255) / 256)  // 123
#define HB 2048                     // radix bins (11 bits)
#define BPC 64                      // fallback blocks per code (grid = 1024)
#define TILE 1024                   // cluster tile entries in LDS
#define CSTRIDE SLOT3               // per-code bucket capacity

struct Scalars {
  double hub;
  double cosSum;
  int n1;
  int nmd;
  float thresh;
  int done;
  int done2;   // k_loss_sel finalize counter
};

__device__ __forceinline__ int voxslot(int b, int vx, int vy, int vz) {
  return ((b * VOXD + vx) * VOXD + vy) * VOXD + vz;
}

// 256-thread (4-wave) inclusive block scan; ws[4] shared scratch.
__device__ __forceinline__ int block_scan256(int v, int* ws) {
  int lane = threadIdx.x & 63, w = threadIdx.x >> 6;
  int s = v;
  #pragma unroll
  for (int off = 1; off < 64; off <<= 1) {
    int t = __shfl_up(s, off, 64);
    if (lane >= off) s += t;
  }
  if (lane == 63) ws[w] = s;
  __syncthreads();
  int add = 0;
  #pragma unroll
  for (int q = 0; q < 4; ++q) if (q < w) add += ws[q];
  __syncthreads();
  return s + add;
}

// ---------------- K1: scatter with packed integer-exact atomics ------------------
__global__ void k_scatter(const float* __restrict__ grid, const int* __restrict__ label,
                          const int* __restrict__ batch,
                          unsigned long long* vA, unsigned long long* vB, int* lmask,
                          int* blCnt, float* blSum, int n) {
  __shared__ int sCnt[NCODE];
  __shared__ float sSum[3 * NCODE];
  int tid = threadIdx.x;
  if (tid < NCODE) sCnt[tid] = 0;
  if (tid < 3 * NCODE) sSum[tid] = 0.f;
  __syncthreads();
  int i = blockIdx.x * blockDim.x + tid;
  if (i < n) {
    float gx = grid[3*i], gy = grid[3*i+1], gz = grid[3*i+2];
    int ix = (int)gx, iy = (int)gy, iz = (int)gz;   // coords are exact small ints
    int vx = (int)floorf(gx * (1.0f/16.0f));
    int vy = (int)floorf(gy * (1.0f/16.0f));
    int vz = (int)floorf(gz * (1.0f/16.0f));
    int b = batch[i], l = label[i];
    int s = voxslot(b, vx, vy, vz);
    atomicAdd(&vA[s], ((unsigned long long)(unsigned)ix << 32) | (unsigned)iy);
    atomicAdd(&vB[s], ((unsigned long long)(unsigned)iz << 24) | 1ULL);
    atomicOr(&lmask[s], 1 << l);
    int bl = b * NCLS + l;
    atomicAdd(&sCnt[bl], 1);
    atomicAdd(&sSum[3*bl], gx); atomicAdd(&sSum[3*bl+1], gy); atomicAdd(&sSum[3*bl+2], gz);
  }
  __syncthreads();
  if (tid < NCODE && sCnt[tid] != 0) atomicAdd(&blCnt[tid], sCnt[tid]);
  if (tid < 3 * NCODE && sSum[tid] != 0.f) atomicAdd(&blSum[tid], sSum[tid]);
}

// ---------------- K2: decode tables -> slot float4 + per-code bucket append ------
// pC = {x, y, z, slot_bits}; c2 recomputed bit-exactly at fallback staging.
__global__ void k_prep(const unsigned long long* vA, const unsigned long long* vB,
                       const int* lmask, float4* ctr, float4* pC, int* codeCnt) {
  __shared__ int lc[NCODE];
  __shared__ int lb[NCODE];
  int tid = threadIdx.x;
  if (tid < NCODE) lc[tid] = 0;
  __syncthreads();
  int s = blockIdx.x * 256 + tid;
  int code = -1, lpos = 0;
  float4 v = make_float4(0.f, 0.f, 0.f, __int_as_float(-2));
  if (s < SLOTS) {
    unsigned long long bq = vB[s];
    unsigned c = (unsigned)(bq & 0xFFFFFFULL);
    if (c > 0) {
      unsigned long long aq = vA[s];
      float fc = (float)c;
      float cx = __fdiv_rn((float)(unsigned)(aq >> 32), fc);
      float cy = __fdiv_rn((float)(unsigned)(aq & 0xFFFFFFFFULL), fc);
      float cz = __fdiv_rn((float)(unsigned)(bq >> 24), fc);
      int m = lmask[s];
      bool pure = (m & (m - 1)) == 0;
      int lbl = __ffs(m) - 1;
      v = make_float4(cx, cy, cz, __int_as_float(pure ? lbl : -1));
      if (pure) {
        code = (s / SLOT3) * NCLS + lbl;
        lpos = atomicAdd(&lc[code], 1);
      }
    }
    ctr[s] = v;
  }
  __syncthreads();
  if (tid < NCODE) lb[tid] = (lc[tid] > 0) ? atomicAdd(&codeCnt[tid], lc[tid]) : 0;
  __syncthreads();
  if (code >= 0) {
    int pos = code * CSTRIDE + lb[code] + lpos;
    pC[pos] = make_float4(v.x, v.y, v.z, __int_as_float(s));
  }
}

// ---------------- K3: probe targets + per-code miss lists + LDS hist -------------
// Legacy (harness-verified).
__global__ void k_targets(const float* __restrict__ grid, const int* __restrict__ label,
                          const int* __restrict__ batch,
                          const float4* __restrict__ ctr,
                          const int* __restrict__ blCnt, const float* __restrict__ blSum,
                          float* tgt, float* mag, int* ghist,
                          int* missPart, int* missCnt, int mstride, int n) {
  __shared__ int wCnt[4][NCODE];
  __shared__ int gBase[NCODE];
  __shared__ int h[HB];
  int tid = threadIdx.x, lane = tid & 63, w = tid >> 6;
  for (int t = tid; t < HB; t += 256) h[t] = 0;
  __syncthreads();
  int i = blockIdx.x * blockDim.x + tid;
  bool active = (i < n);
  bool miss = false;
  int mcode = -1;

  if (active) {
    float gx = grid[3*i], gy = grid[3*i+1], gz = grid[3*i+2];
    int vx = (int)floorf(gx * (1.0f/16.0f));
    int vy = (int)floorf(gy * (1.0f/16.0f));
    int vz = (int)floorf(gz * (1.0f/16.0f));
    int b = batch[i], l = label[i];
    int s = voxslot(b, vx, vy, vz);

    float4 own = ctr[s];
    bool purept = (__float_as_int(own.w) >= 0);

    int bl = b * NCLS + l;
    float fbc = (float)max(blCnt[bl], 1);
    float gcx = __fdiv_rn(blSum[3*bl],   fbc);
    float gcy = __fdiv_rn(blSum[3*bl+1], fbc);
    float gcz = __fdiv_rn(blSum[3*bl+2], fbc);

    float dx = __fsub_rn(gcx, own.x);
    float dy = __fsub_rn(gcy, own.y);
    float dz = __fsub_rn(gcz, own.z);
    int sgx = (dx > 0.f) ? 1 : ((dx < 0.f) ? -1 : 0);
    int sgy = (dy > 0.f) ? 1 : ((dy < 0.f) ? -1 : 0);
    int sgz = (dz > 0.f) ? 1 : ((dz < 0.f) ? -1 : 0);

    int ax1 = vx + sgx,     ay1 = vy + sgy,     az1 = vz + sgz;
    int ax2 = vx + 2 * sgx, ay2 = vy + 2 * sgy, az2 = vz + 2 * sgz;
    bool v1 = (unsigned)ax1 < (unsigned)VOXD && (unsigned)ay1 < (unsigned)VOXD &&
              (unsigned)az1 < (unsigned)VOXD;
    bool v2 = (unsigned)ax2 < (unsigned)VOXD && (unsigned)ay2 < (unsigned)VOXD &&
              (unsigned)az2 < (unsigned)VOXD;

    float4 q1 = make_float4(0.f, 0.f, 0.f, __int_as_float(-3));
    float4 q2 = q1;
    if (v1) q1 = ctr[voxslot(b, ax1, ay1, az1)];
    if (v2) q2 = ctr[voxslot(b, ax2, ay2, az2)];

    bool hit1 = v1 && (__float_as_int(q1.w) == l);
    bool hit2 = v2 && (__float_as_int(q2.w) == l);
    bool hit = hit1 || hit2;

    float tx = hit1 ? q1.x : (hit2 ? q2.x : gx);
    float ty = hit1 ? q1.y : (hit2 ? q2.y : gy);
    float tz = hit1 ? q1.z : (hit2 ? q2.z : gz);

    tgt[3*i] = tx; tgt[3*i+1] = ty; tgt[3*i+2] = tz;
    miss = (!purept && !hit);
    if (miss) {
      mcode = bl;
    } else {
      float tox = __fsub_rn(tx, gx), toy = __fsub_rn(ty, gy), toz = __fsub_rn(tz, gz);
      float ssq = __fadd_rn(__fadd_rn(__fmul_rn(tox,tox), __fmul_rn(toy,toy)),
                            __fmul_rn(toz,toz));
      float m = (ssq > 0.f) ? sqrtf(ssq) : 0.f;
      mag[i] = m;
      atomicAdd(&h[__float_as_uint(m) >> 21], 1);
    }
  }
  int myrank = 0;
  #pragma unroll
  for (int c = 0; c < NCODE; ++c) {
    unsigned long long mb = __ballot(mcode == c);
    if (lane == 0) wCnt[w][c] = __popcll(mb);
    if (mcode == c) myrank = __popcll(mb & ((1ULL << lane) - 1ULL));
  }
  __syncthreads();
  if (tid < NCODE) {
    int tot = wCnt[0][tid] + wCnt[1][tid] + wCnt[2][tid] + wCnt[3][tid];
    gBase[tid] = (tot > 0) ? atomicAdd(&missCnt[tid], tot) : 0;
  }
  __syncthreads();
  if (miss) {
    int base = gBase[mcode];
    for (int q = 0; q < 4; ++q) if (q < w) base += wCnt[q][mcode];
    missPart[mcode * mstride + base + myrank] = i;
  }
  for (int t = tid; t < HB; t += 256) {
    int c = h[t];
    if (c != 0) atomicAdd(&ghist[t], c);
  }
}

// ---------------- K4: fallback, 64 misses/block, cluster-split across 4 waves ----
// (Round-8-verified: cluster-split + per-block LDS histogram.)
__global__ void __launch_bounds__(256) k_fallback(
    const float* __restrict__ grid,
    const float4* __restrict__ pC,
    const float4* __restrict__ ctr,
    const int* __restrict__ codeCnt,
    const int* __restrict__ missPart, const int* __restrict__ missCnt,
    float* tgt, float* mag, int* ghist, int mstride) {
  __shared__ float4 tile4[TILE];                 // 16 KB {x,y,z,c2}
  __shared__ int    stile[TILE];                 //  4 KB slot ids
  __shared__ unsigned long long bkeyw[4][64];    //  2 KB per-wave best keys
  __shared__ int h[HB];                          //  8 KB per-block histogram
  int tid = threadIdx.x, lane = tid & 63, w = tid >> 6;
  int c = blockIdx.x / BPC;
  int y = blockIdx.x % BPC;
  int mc = missCnt[c];
  if (y * 64 >= mc) return;                      // uniform early-out (no hist yet)
  int cc = codeCnt[c];
  int j0 = c * CSTRIDE;
  const int* mlist = missPart + c * mstride;

  for (int t = tid; t < HB; t += 256) h[t] = 0;
  __syncthreads();

  for (int t0 = y * 64; t0 < mc; t0 += BPC * 64) {
    int t = t0 + lane;
    bool valid = (t < mc);
    int idx = 0;
    float gx = 0.f, gy = 0.f, gz = 0.f, p2 = 0.f;
    if (valid) {
      idx = mlist[t];
      gx = grid[3*idx]; gy = grid[3*idx+1]; gz = grid[3*idx+2];
      p2 = __fadd_rn(__fadd_rn(__fmul_rn(gx,gx), __fmul_rn(gy,gy)),
                     __fmul_rn(gz,gz));
    }
    unsigned long long key = 0xFFFFFFFFFFFFFFFFULL;
    for (int tb = 0; tb < cc; tb += TILE) {
      int m = min(TILE, cc - tb);
      __syncthreads();
      for (int j = tid; j < m; j += 256) {
        float4 cl = pC[j0 + tb + j];
        float c2 = __fadd_rn(__fadd_rn(__fmul_rn(cl.x,cl.x), __fmul_rn(cl.y,cl.y)),
                             __fmul_rn(cl.z,cl.z));
        tile4[j] = make_float4(cl.x, cl.y, cl.z, c2);
        stile[j] = __float_as_int(cl.w);
      }
      __syncthreads();
      #pragma unroll 4
      for (int j = w; j < m; j += 4) {
        float4 cl = tile4[j];                    // broadcast read
        float dot = __fadd_rn(__fadd_rn(__fmul_rn(gx,cl.x), __fmul_rn(gy,cl.y)),
                              __fmul_rn(gz,cl.z));
        float d2 = __fadd_rn(__fsub_rn(p2, __fmul_rn(2.0f, dot)), cl.w);
        unsigned fb = __float_as_uint(d2);
        fb = (fb >> 31) ? ~fb : (fb | 0x80000000u);
        unsigned long long k2 = ((unsigned long long)fb << 32) | (unsigned)stile[j];
        if (k2 < key) key = k2;
      }
    }
    bkeyw[w][lane] = key;
    __syncthreads();
    if (w == 0 && valid) {
      unsigned long long k0 = bkeyw[0][lane];
      unsigned long long k1 = bkeyw[1][lane];
      unsigned long long k2_ = bkeyw[2][lane];
      unsigned long long k3 = bkeyw[3][lane];
      unsigned long long kk = k0 < k1 ? k0 : k1;
      unsigned long long kh = k2_ < k3 ? k2_ : k3;
      if (kh < kk) kk = kh;
      float mv = 0.f;
      if (cc > 0) {
        int slot = (int)(unsigned)(kk & 0xFFFFFFFFULL);
        float4 cl = ctr[slot];
        tgt[3*idx] = cl.x; tgt[3*idx+1] = cl.y; tgt[3*idx+2] = cl.z;
        float tox = __fsub_rn(cl.x, gx), toy = __fsub_rn(cl.y, gy),
              toz = __fsub_rn(cl.z, gz);
        float ssq = __fadd_rn(__fadd_rn(__fmul_rn(tox,tox), __fmul_rn(toy,toy)),
                              __fmul_rn(toz,toz));
        mv = (ssq > 0.f) ? sqrtf(ssq) : 0.f;
      }
      mag[idx] = mv;
      atomicAdd(&h[__float_as_uint(mv) >> 21], 1);
    }
    __syncthreads();                             // bkeyw/h reuse next pass
  }

  // flush aggregated histogram
  for (int t = tid; t < HB; t += 256) {
    int cv = h[t];
    if (cv != 0) atomicAdd(&ghist[t], cv);
  }
}

// ---------------- K5: loss + exact quantile, distributed finalize prep -----------
// v2 (round 9): the fully-parallel classify pass now (a) pre-aggregates the
// MID-LEVEL histograms of boundary-bin points into global gh2A/gh2B (per-block
// LDS hist + aggregated flush -- the proven k_targets pattern), and (b) stores
// each deferred point's precomputed (bits, hub, cos) contributions contiguously.
// The last-block tail then: scans gh2A/gh2B (no defer pass), does ONE uint4-
// batched pass over dBits for the low-level hist, and ONE contiguous streaming
// pass over (dBits,dHC) for the deferred loss. All arithmetic identical to the
// round-8-verified kernel; only aggregation points moved.
__global__ void __launch_bounds__(256) k_loss_sel(
    const float* __restrict__ pred, const float* __restrict__ grid,
    const float* __restrict__ tgt, const float* __restrict__ mag,
    const int* __restrict__ ghist, int* gh2A, int* gh2B,
    unsigned* dBits, double2* dHC, int* uCnt,
    Scalars* sc, float* out, int n, int nblocks, int r0, int r1, double tfrac) {
  __shared__ int h[HB];            // 8 KB (step-2 hA2; tail reuse)
  __shared__ int h2[HB];           // 8 KB (step-2 hB2; tail reuse)
  __shared__ int ws[4];
  __shared__ int s_misc[8];
  __shared__ double shH[256];
  __shared__ double shC[256];
  __shared__ int shN[256];
  __shared__ int shM[256];
  __shared__ int sLast;
  __shared__ float sTh;
  int tid = threadIdx.x, lane = tid & 63;

  // ---- step 1: coarse bins from ghist (every block; identical results) ----
  int base8 = tid * 8;
  {
    int cbin[8];
    int s = 0;
    #pragma unroll
    for (int k = 0; k < 8; ++k) { cbin[k] = ghist[base8 + k]; s += cbin[k]; }
    int incl = block_scan256(s, ws);
    int lo = incl - s;
    if (r0 >= lo && r0 < lo + s) {
      int acc = lo;
      #pragma unroll
      for (int k = 0; k < 8; ++k) {
        if (r0 < acc + cbin[k]) { s_misc[0] = base8 + k; s_misc[1] = r0 - acc; break; }
        acc += cbin[k];
      }
    }
    if (r1 >= lo && r1 < lo + s) {
      int acc = lo;
      #pragma unroll
      for (int k = 0; k < 8; ++k) {
        if (r1 < acc + cbin[k]) { s_misc[2] = base8 + k; s_misc[3] = r1 - acc; break; }
        acc += cbin[k];
      }
    }
  }
  __syncthreads();
  int binA = s_misc[0], rA = s_misc[1], binB = s_misc[2], rB = s_misc[3];

  // ---- step 2: classify; sure sums; deferred -> contributions + mid LDS hist ----
  for (int t = tid; t < HB; t += 256) { h[t] = 0; h2[t] = 0; }
  __syncthreads();

  int i = blockIdx.x * 256 + tid;
  double hub = 0.0, cs = 0.0;
  int c1 = 0, cmd = 0;
  bool dfr = false;
  unsigned bits = 0;
  double dhub = 0.0, dcs = 0.0;
  if (i < n) {
    float m = mag[i];
    bits = __float_as_uint(m);
    int cb = (int)(bits >> 21);
    bool boundary = (cb == binA || cb == binB);
    if (boundary || cb < binA) {
      // shared verified huber/cos arithmetic
      float tox = __fsub_rn(tgt[3*i],   grid[3*i]);
      float toy = __fsub_rn(tgt[3*i+1], grid[3*i+1]);
      float toz = __fsub_rn(tgt[3*i+2], grid[3*i+2]);
      float px = pred[3*i], py = pred[3*i+1], pz = pred[3*i+2];
      float d0 = __fsub_rn(px, tox), d1 = __fsub_rn(py, toy), d2 = __fsub_rn(pz, toz);
      float a0 = fabsf(d0), a1 = fabsf(d1), a2 = fabsf(d2);
      float h0 = (a0 < 1.f) ? __fmul_rn(__fmul_rn(0.5f, d0), d0) : __fsub_rn(a0, 0.5f);
      float h1 = (a1 < 1.f) ? __fmul_rn(__fmul_rn(0.5f, d1), d1) : __fsub_rn(a1, 0.5f);
      float h2v = (a2 < 1.f) ? __fmul_rn(__fmul_rn(0.5f, d2), d2) : __fsub_rn(a2, 0.5f);
      double hubv = (double)h0 + (double)h1 + (double)h2v;
      double csv = 0.0;
      if (m > 0.f) {
        float ps = __fadd_rn(__fadd_rn(__fmul_rn(px,px), __fmul_rn(py,py)), __fmul_rn(pz,pz));
        float pn = (ps > 0.f) ? sqrtf(ps) : 0.f;
        float dotp = __fadd_rn(__fadd_rn(__fmul_rn(px,tox), __fmul_rn(py,toy)),
                               __fmul_rn(pz,toz));
        float den = fmaxf(__fmul_rn(pn, m), 1e-4f);
        csv = (double)__fdiv_rn(dotp, den);
      }
      if (boundary) {
        dfr = true;
        dhub = hubv; dcs = csv;
        if (cb == binA) atomicAdd(&h[(bits >> 10) & 0x7FF], 1);
        if (cb == binB) atomicAdd(&h2[(bits >> 10) & 0x7FF], 1);
      } else {
        c1 = 1;
        hub = hubv;
        if (m > 0.f) { cmd = 1; cs = csv; }
      }
    }
  }
  {
    unsigned long long mb = __ballot(dfr);
    int mcp = __popcll(mb);
    int bs = 0;
    if (lane == 0 && mcp > 0) bs = atomicAdd(uCnt, mcp);
    bs = __shfl(bs, 0, 64);
    if (dfr) {
      int pos = bs + __popcll(mb & ((1ULL << lane) - 1ULL));
      dBits[pos] = bits;
      dHC[pos] = make_double2(dhub, dcs);
    }
  }
  __syncthreads();
  // flush mid-level LDS hists (aggregated, sparse)
  for (int t = tid; t < HB; t += 256) {
    int a = h[t];
    if (a != 0) atomicAdd(&gh2A[t], a);
    int b = h2[t];
    if (b != 0) atomicAdd(&gh2B[t], b);
  }

  shH[tid] = hub; shC[tid] = cs; shN[tid] = c1; shM[tid] = cmd;
  __syncthreads();
  for (int off = 128; off > 0; off >>= 1) {
    if (tid < off) {
      shH[tid] += shH[tid+off];
      shC[tid] += shC[tid+off];
      shN[tid] += shN[tid+off];
      shM[tid] += shM[tid+off];
    }
    __syncthreads();
  }
  if (tid == 0) {
    atomicAdd(&sc->hub, shH[0]);
    atomicAdd(&sc->cosSum, shC[0]);
    atomicAdd(&sc->n1, shN[0]);
    atomicAdd(&sc->nmd, shM[0]);
    __threadfence();
    int d = atomicAdd(&sc->done2, 1);
    sLast = (d == nblocks - 1) ? 1 : 0;
  }
  __syncthreads();
  if (!sLast) return;
  __threadfence();   // acquire: all blocks' defer/gh2 writes + partial sums

  int U = atomicAdd(uCnt, 0);

  // ---- step 3: mid-level scan directly from global gh2A/gh2B (no defer pass) ----
  {
    int a8[8], sA = 0;
    #pragma unroll
    for (int k = 0; k < 8; ++k) { a8[k] = gh2A[base8 + k]; sA += a8[k]; }
    int inclA = block_scan256(sA, ws);
    int accA = inclA - sA;
    #pragma unroll
    for (int k = 0; k < 8; ++k) {
      if (rA >= accA && rA < accA + a8[k]) { s_misc[4] = base8 + k; s_misc[5] = rA - accA; }
      accA += a8[k];
    }
    int b8[8], sB = 0;
    #pragma unroll
    for (int k = 0; k < 8; ++k) { b8[k] = gh2B[base8 + k]; sB += b8[k]; }
    int inclB = block_scan256(sB, ws);
    int accB = inclB - sB;
    #pragma unroll
    for (int k = 0; k < 8; ++k) {
      if (rB >= accB && rB < accB + b8[k]) { s_misc[6] = base8 + k; s_misc[7] = rB - accB; }
      accB += b8[k];
    }
  }
  __syncthreads();
  int subA = s_misc[4], subRA = s_misc[5], subB = s_misc[6], subRB = s_misc[7];

  // ---- step 4: low-level hist, ONE uint4-batched pass over dBits ----
  for (int t = tid; t < 1024; t += 256) { h[t] = 0; h2[t] = 0; }
  __syncthreads();
  {
    const uint4* b4 = (const uint4*)dBits;
    int nv = U >> 2;
    for (int v = tid; v < nv; v += 256) {
      uint4 u = b4[v];
      unsigned bb[4] = { u.x, u.y, u.z, u.w };
      #pragma unroll
      for (int k = 0; k < 4; ++k) {
        unsigned b0 = bb[k];
        int cb = (int)(b0 >> 21);
        if (cb == binA && (int)((b0 >> 10) & 0x7FF) == subA) atomicAdd(&h[b0 & 0x3FF], 1);
        if (cb == binB && (int)((b0 >> 10) & 0x7FF) == subB) atomicAdd(&h2[b0 & 0x3FF], 1);
      }
    }
    for (int t = (nv << 2) + tid; t < U; t += 256) {
      unsigned b0 = dBits[t];
      int cb = (int)(b0 >> 21);
      if (cb == binA && (int)((b0 >> 10) & 0x7FF) == subA) atomicAdd(&h[b0 & 0x3FF], 1);
      if (cb == binB && (int)((b0 >> 10) & 0x7FF) == subB) atomicAdd(&h2[b0 & 0x3FF], 1);
    }
  }
  __syncthreads();
  {
    int base4 = tid * 4;
    int la[4], sA = 0;
    #pragma unroll
    for (int k = 0; k < 4; ++k) { la[k] = h[base4 + k]; sA += la[k]; }
    int inclA = block_scan256(sA, ws);
    int accA = inclA - sA;
    #pragma unroll
    for (int k = 0; k < 4; ++k) {
      if (subRA >= accA && subRA < accA + la[k]) s_misc[0] = base4 + k;
      accA += la[k];
    }
    int lb4[4], sB = 0;
    #pragma unroll
    for (int k = 0; k < 4; ++k) { lb4[k] = h2[base4 + k]; sB += lb4[k]; }
    int inclB = block_scan256(sB, ws);
    int accB = inclB - sB;
    #pragma unroll
    for (int k = 0; k < 4; ++k) {
      if (subRB >= accB && subRB < accB + lb4[k]) s_misc[1] = base4 + k;
      accB += lb4[k];
    }
  }
  __syncthreads();
  if (tid == 0) {
    unsigned va = ((unsigned)binA << 21) | ((unsigned)subA << 10) | (unsigned)s_misc[0];
    unsigned vb = ((unsigned)binB << 21) | ((unsigned)subB << 10) | (unsigned)s_misc[1];
    double a = (double)__uint_as_float(va);
    double b = (double)__uint_as_float(vb);
    double th = (tfrac >= 0.5) ? (b - (b - a) * (1.0 - tfrac)) : (a + (b - a) * tfrac);
    sc->thresh = (float)th;
    sTh = (float)th;
  }
  __syncthreads();
  float th = sTh;

  // ---- step 5: deferred loss, contiguous stream over (dBits, dHC) ----
  double hub2 = 0.0, cs2 = 0.0;
  int c12 = 0, cmd2 = 0;
  for (int t = tid; t < U; t += 256) {
    unsigned v = dBits[t];
    float m = __uint_as_float(v);
    double2 hc = dHC[t];     // unconditional load (contiguous, good ILP)
    if (m <= th) {
      c12 += 1;
      hub2 += hc.x;
      if (m > 0.f) { cmd2 += 1; cs2 += hc.y; }
    }
  }
  shH[tid] = hub2; shC[tid] = cs2; shN[tid] = c12; shM[tid] = cmd2;
  __syncthreads();
  for (int off = 128; off > 0; off >>= 1) {
    if (tid < off) {
      shH[tid] += shH[tid+off];
      shC[tid] += shC[tid+off];
      shN[tid] += shN[tid+off];
      shM[tid] += shM[tid+off];
    }
    __syncthreads();
  }
  if (tid == 0) {
    double th_hub = atomicAdd(&sc->hub, 0.0) + shH[0];
    double th_cos = atomicAdd(&sc->cosSum, 0.0) + shC[0];
    int n1 = atomicAdd(&sc->n1, 0) + shN[0];
    int nmd = atomicAdd(&sc->nmd, 0) + shM[0];
    double l1 = (n1 > 0) ? th_hub / fmax((double)n1 * 3.0, 1.0) : 0.0;
    double ld = (nmd > 0) ? (1.0 - th_cos / fmax((double)nmd, 1.0)) : 0.0;
    out[0] = (float)l1;
    out[1] = (float)ld;
  }
}

extern "C" void kernel_launch(void* const* d_in, const int* in_sizes, int n_in,
                              void* d_out, int out_size, void* d_ws, size_t ws_size,
                              hipStream_t stream) {
  const float* pred  = (const float*)d_in[0];
  const float* grid  = (const float*)d_in[1];
  const int*   label = (const int*)d_in[2];
  const int*   batch = (const int*)d_in[3];
  int n = in_sizes[2];
  int mstride = n / 4;

  char* p = (char*)d_ws;
  auto take = [&](size_t bytes) -> char* {
    char* r = p;
    p += (bytes + 255) & ~(size_t)255;
    return r;
  };
  // ---- zero-init region (one hipMemsetAsync covers all of it) ----
  char* zbase = p;
  unsigned long long* vA = (unsigned long long*)take((size_t)SLOTS*8);
  unsigned long long* vB = (unsigned long long*)take((size_t)SLOTS*8);
  int*    lmask    = (int*)   take((size_t)SLOTS*4);
  int*    codeCnt  = (int*)   take(NCODE*4);
  int*    missCnt  = (int*)   take(NCODE*4);
  int*    blCnt    = (int*)   take(16*4);
  float*  blSum    = (float*) take(48*4);
  int*    ghist    = (int*)   take((size_t)HB*4);
  int*    gh2A     = (int*)   take((size_t)HB*4);
  int*    gh2B     = (int*)   take((size_t)HB*4);
  int*    uCnt     = (int*)   take(4);
  Scalars* sc      = (Scalars*)take(sizeof(Scalars));
  size_t zbytes = (size_t)(p - zbase);
  // ---- uninitialized buffers ----
  float4* ctr      = (float4*)take((size_t)SLOTS*16);
  float4* pC       = (float4*)take((size_t)NCODE*CSTRIDE*16);
  float*  tgt      = (float*) take((size_t)n*3*4);
  float*  mag      = (float*) take((size_t)n*4);
  int*    missPart = (int*)   take((size_t)NCODE*mstride*4);
  unsigned* dBits  = (unsigned*)take((size_t)n*4);
  double2*  dHC    = (double2*) take((size_t)n*16);

  int nb = (n + 255) / 256;
  int nfb = NCODE * BPC;

  double vi = 0.99 * (double)(n - 1);
  int r0 = (int)vi;
  int r1 = r0 + 1; if (r1 > n - 1) r1 = n - 1;
  double tfrac = vi - (double)r0;

  hipMemsetAsync(zbase, 0, zbytes, stream);
  k_scatter<<<nb, 256, 0, stream>>>(grid, label, batch, vA, vB, lmask,
                                    blCnt, blSum, n);
  k_prep<<<NBLK, 256, 0, stream>>>(vA, vB, lmask, ctr, pC, codeCnt);
  k_targets<<<nb, 256, 0, stream>>>(grid, label, batch, ctr, blCnt, blSum,
                                    tgt, mag, ghist, missPart, missCnt, mstride, n);
  k_fallback<<<nfb, 256, 0, stream>>>(grid, pC, ctr, codeCnt,
                                      missPart, missCnt, tgt, mag, ghist, mstride);
  k_loss_sel<<<nb, 256, 0, stream>>>(pred, grid, tgt, mag, ghist, gh2A, gh2B,
                                     dBits, dHC, uCnt, sc, (float*)d_out,
                                     n, nb, r0, r1, tfrac);
}